// Round 7
// baseline (376.449 us; speedup 1.0000x reference)
//
#include <hip/hip_runtime.h>

typedef _Float16 f16;
typedef __attribute__((ext_vector_type(4))) _Float16 f16x4;
typedef __attribute__((ext_vector_type(8))) _Float16 f16x8;
typedef __attribute__((ext_vector_type(4))) float f32x4;

#define GLDS16(gp, lp)                                                        \
  __builtin_amdgcn_global_load_lds(                                           \
      (const __attribute__((address_space(1))) void*)(gp),                    \
      (__attribute__((address_space(3))) void*)(lp), 16, 0, 0)

__device__ __forceinline__ f32x4 mfma16(f16x8 a, f16x8 b, f32x4 c) {
  return __builtin_amdgcn_mfma_f32_16x16x32_f16(a, b, c, 0, 0, 0);
}

// ---------------- fused prep: cvt x2 | mask | weight transposes ----------------
// grid.x: [0,4096) cvt qin (scale folded); [4096,8192) cvt kvin;
//         [8192,9216) mask; [9216,10240) tr32 of wq/wk/wv/wo
__global__ __launch_bounds__(256) void k_prep(
    const float* __restrict__ qin, const float* __restrict__ kvin,
    const int* __restrict__ qt, const float* __restrict__ wq,
    const float* __restrict__ wk, const float* __restrict__ wv,
    const float* __restrict__ wo, f16* __restrict__ Xq, f16* __restrict__ Xkv,
    unsigned* __restrict__ Mb, f16* __restrict__ WqT, f16* __restrict__ WkT,
    f16* __restrict__ WvT, f16* __restrict__ WoT) {
  __shared__ float tile[64][65];
  const int bx = blockIdx.x, tid = threadIdx.x;
  if (bx < 8192) {
    const float* s = bx < 4096 ? qin : kvin;
    f16* d = bx < 4096 ? Xq : Xkv;
    const float sc = bx < 4096 ? 0.18033688f : 1.0f;  // 0.125*log2(e) into Q
    int i = ((bx & 4095) * 256 + tid) * 4;
    float4 v = *(const float4*)(s + i);
    f16x4 h;
    h[0] = (f16)(v.x * sc); h[1] = (f16)(v.y * sc);
    h[2] = (f16)(v.z * sc); h[3] = (f16)(v.w * sc);
    *(f16x4*)(d + i) = h;
    return;
  }
  if (bx < 9216) {
    int w = (bx - 8192) * 256 + tid;
    const int* p = qt + (long)w * 32;
    unsigned m = 0;
#pragma unroll
    for (int j4 = 0; j4 < 8; ++j4) {
      int4 v = *(const int4*)(p + j4 * 4);
      m |= (v.x == 0 ? 1u : 0u) << (j4 * 4 + 0);
      m |= (v.y == 0 ? 1u : 0u) << (j4 * 4 + 1);
      m |= (v.z == 0 ? 1u : 0u) << (j4 * 4 + 2);
      m |= (v.w == 0 ? 1u : 0u) << (j4 * 4 + 3);
    }
    Mb[w] = m;
    return;
  }
  // weight transposes: dst[c][r] = src[r][c], f32 -> f16
  int sgt = bx - 9216, which = sgt >> 8, t = sgt & 255;
  const float* src;
  f16* dst;
  int sldr, r0, c0;
  const int dldr = 1024;
  if (which == 0) {
    src = wq + (long)(t >> 4) * 65536; dst = WqT + (long)(t >> 4) * 65536;
    sldr = 64; r0 = (t & 15) * 64; c0 = 0;
  } else if (which == 1) {
    src = wk + (long)(t >> 4) * 65536; dst = WkT + (long)(t >> 4) * 65536;
    sldr = 64; r0 = (t & 15) * 64; c0 = 0;
  } else if (which == 2) {
    src = wv + (long)(t >> 4) * 65536; dst = WvT + (long)(t >> 4) * 65536;
    sldr = 64; r0 = (t & 15) * 64; c0 = 0;
  } else {
    src = wo; dst = WoT;
    sldr = 1024; r0 = (t >> 4) * 64; c0 = (t & 15) * 64;
  }
  int r = tid >> 2, cq = (tid & 3) * 16;
#pragma unroll
  for (int j = 0; j < 16; j += 4) {
    float4 v = *(const float4*)(src + (long)(r0 + r) * sldr + c0 + cq + j);
    tile[r][cq + j] = v.x; tile[r][cq + j + 1] = v.y;
    tile[r][cq + j + 2] = v.z; tile[r][cq + j + 3] = v.w;
  }
  __syncthreads();
  int c = tid >> 2, rq = (tid & 3) * 16;
  f16x8 h0, h1;
#pragma unroll
  for (int j = 0; j < 8; ++j) h0[j] = (f16)tile[rq + j][c];
#pragma unroll
  for (int j = 0; j < 8; ++j) h1[j] = (f16)tile[rq + 8 + j][c];
  f16* dp = dst + (long)(c0 + c) * dldr + r0 + rq;
  *(f16x8*)dp = h0;
  *(f16x8*)(dp + 8) = h1;
}

// ---------------- GEMM body: C[LxN] = A[LxK] * Bt[NxK]^T ----------------
// mode 0: f16 C row-major; mode 1: f32 C row-major;
// mode 2: V-transposed write — Cout is Vt (b,h,64,T), cols are [1024,2048)
__device__ __forceinline__ void gemm_body(const f16* __restrict__ A,
                                          const f16* __restrict__ Bt,
                                          void* __restrict__ Cout, int Kd,
                                          int N, int bxx, int byy, int mode,
                                          f16* Al, f16* Bl) {
  const int tid = threadIdx.x, l = tid & 63, w = tid >> 6;
  const int wm = w >> 1, wn = w & 1;
  const int m0 = byy * 128, n0 = bxx * 128;
  const int lr = l >> 2;
  const int lc = (l & 3) * 8;
  const int fr = l & 15;
  const int fk = (l >> 4) * 8;
  f32x4 acc[4][4] = {};
  for (int k0 = 0; k0 < Kd; k0 += 32) {
#pragma unroll
    for (int rd = 0; rd < 2; ++rd) {
      GLDS16(A + (long)(m0 + rd * 64 + w * 16 + lr) * Kd + k0 + lc,
             (char*)Al + rd * 4096 + w * 1024);
      GLDS16(Bt + (long)(n0 + rd * 64 + w * 16 + lr) * Kd + k0 + lc,
             (char*)Bl + rd * 4096 + w * 1024);
    }
    __syncthreads();
    f16x8 af[4], bf[4];
#pragma unroll
    for (int i = 0; i < 4; ++i) {
      af[i] = *(const f16x8*)(Al + (wm * 64 + i * 16 + fr) * 32 + fk);
      bf[i] = *(const f16x8*)(Bl + (wn * 64 + i * 16 + fr) * 32 + fk);
    }
#pragma unroll
    for (int i = 0; i < 4; ++i)
#pragma unroll
      for (int j = 0; j < 4; ++j)
        acc[i][j] = mfma16(af[i], bf[j], acc[i][j]);
    __syncthreads();
  }
  const int rb = (l >> 4) * 4;
#pragma unroll
  for (int i = 0; i < 4; ++i)
#pragma unroll
    for (int j = 0; j < 4; ++j) {
      int row = m0 + wm * 64 + i * 16 + rb;
      int col = n0 + wn * 64 + j * 16 + fr;
      if (mode == 2) {
        // Vt[b][col-1024][t] ; 4 consecutive t's = contiguous f16x4
        int col2 = col - 1024;
        long off = (long)(row >> 11) * 2097152 + (long)col2 * 2048 +
                   (row & 2047);
        f16x4 o;
        o[0] = (f16)acc[i][j][0]; o[1] = (f16)acc[i][j][1];
        o[2] = (f16)acc[i][j][2]; o[3] = (f16)acc[i][j][3];
        *(f16x4*)((f16*)Cout + off) = o;
      } else {
#pragma unroll
        for (int r = 0; r < 4; ++r) {
          if (mode == 1)
            ((float*)Cout)[(long)(row + r) * N + col] = acc[i][j][r];
          else
            ((f16*)Cout)[(long)(row + r) * N + col] = (f16)acc[i][j][r];
        }
      }
    }
}

// Q-proj (x<8), K-proj (x in [8,16)), V-proj transposed (x in [16,24))
__global__ __launch_bounds__(256) void k_gemm_qkv(
    const f16* __restrict__ Xq, const f16* __restrict__ WqT,
    f16* __restrict__ Qm, const f16* __restrict__ Xkv,
    const f16* __restrict__ WkT, f16* __restrict__ KVm,
    f16* __restrict__ Vt) {
  __shared__ __attribute__((aligned(16))) f16 Al[128 * 32];
  __shared__ __attribute__((aligned(16))) f16 Bl[128 * 32];
  if (blockIdx.x < 8) {
    gemm_body(Xq, WqT, (void*)Qm, 1024, 1024, blockIdx.x, blockIdx.y, 0, Al,
              Bl);
  } else {
    int bxx = blockIdx.x - 8;
    if (bxx < 8)
      gemm_body(Xkv, WkT, (void*)KVm, 1024, 2048, bxx, blockIdx.y, 0, Al, Bl);
    else
      gemm_body(Xkv, WkT, (void*)Vt, 1024, 2048, bxx, blockIdx.y, 2, Al, Bl);
  }
}

__global__ __launch_bounds__(256) void k_gemm_out(const f16* __restrict__ Pre,
                                                  const f16* __restrict__ WoT,
                                                  float* __restrict__ out) {
  __shared__ __attribute__((aligned(16))) f16 Al[128 * 32];
  __shared__ __attribute__((aligned(16))) f16 Bl[128 * 32];
  gemm_body(Pre, WoT, (void*)out, 1024, 1024, blockIdx.x, blockIdx.y, 1, Al,
            Bl);
}

// ---------------- fused attention (QBLK=32, 512 threads, 8 waves) ----------
// wave w: q-half (w&1), t-slice 512 (w>>1). Swapped QK^T; no max pass; exp2
// (scale pre-folded into Q); e in registers; att from registers (NT);
// per-wave PV partials via private LDS chunks. NO min-occupancy bound.
__global__ __launch_bounds__(512) void k_attn(
    const f16* __restrict__ Qm, const f16* __restrict__ Km,
    const f16* __restrict__ Vt, const unsigned* __restrict__ mb,
    float* __restrict__ att, f16* __restrict__ Pre, int ldk) {
  __shared__ unsigned mloc[32 * 68];
  __shared__ float wsum[8][16];
  __shared__ float rsum[32];
  __shared__ __attribute__((aligned(16))) f16 ebuf[8][16 * 136];
  const int qt = blockIdx.x, h = blockIdx.y, b = blockIdx.z;
  const int q0 = qt * 32;
  const int tid = threadIdx.x, l = tid & 63, w = tid >> 6;
  const int fr = l & 15, fg = l >> 4;
  const int qh = w & 1;   // q-half (16 rows)
  const int ts = w >> 1;  // t-slice index (512 cols)
  const int qrow = qh * 16 + fr;

  // stage active-bitmask (32 rows x 64 words, stride 68)
  for (int i = tid; i < 2048; i += 512)
    mloc[(i >> 6) * 68 + (i & 63)] =
        mb[(long)(b * 2048 + q0 + (i >> 6)) * 64 + (i & 63)];

  // Q fragment (B-operand); kscale*log2(e) already folded in upstream
  const f16* qb = Qm + (long)(b * 2048 + q0 + qrow) * 1024 + h * 64 + fg * 8;
  f16x8 qf0 = *(const f16x8*)qb;
  f16x8 qf1 = *(const f16x8*)(qb + 32);
  __syncthreads();

  // ---- Phase 1: S^T = K Q^T -> exp2 inline -> e (f16) in regs + row sums ----
  const f16* kb = Km + (long)(b * 2048 + ts * 512 + fr) * ldk + h * 64 + fg * 8;
  f16x8 ka0[2], ka1[2];
#pragma unroll
  for (int p = 0; p < 2; ++p) {
    ka0[p] = *(const f16x8*)(kb + (long)p * 16 * ldk);
    ka1[p] = *(const f16x8*)(kb + (long)p * 16 * ldk + 32);
  }
  f16x4 s16[32];
  float sm[4] = {0.f, 0.f, 0.f, 0.f};
#pragma unroll
  for (int i = 0; i < 32; ++i) {
    f16x8 k0 = ka0[i & 1], k1 = ka1[i & 1];
    if (i < 30) {
      ka0[i & 1] = *(const f16x8*)(kb + (long)(i + 2) * 16 * ldk);
      ka1[i & 1] = *(const f16x8*)(kb + (long)(i + 2) * 16 * ldk + 32);
    }
    f32x4 s = {};
    s = mfma16(k0, qf0, s);
    s = mfma16(k1, qf1, s);
    unsigned bits =
        (mloc[qrow * 68 + ts * 16 + (i >> 1)] >> ((i & 1) * 16 + fg * 4)) &
        0xFu;
    f16x4 e4;
#pragma unroll
    for (int r = 0; r < 4; ++r) {
      float ev = ((bits >> r) & 1) ? __builtin_amdgcn_exp2f(s[r]) : 0.f;
      sm[r] += ev;
      e4[r] = (f16)ev;
    }
    s16[i] = e4;
  }
  float sa = (sm[0] + sm[1]) + (sm[2] + sm[3]);
  sa += __shfl_xor(sa, 16, 64);
  sa += __shfl_xor(sa, 32, 64);
  if (l < 16) wsum[w][fr] = sa;
  __syncthreads();
  float tot = (wsum[qh][fr] + wsum[qh + 2][fr]) +
              (wsum[qh + 4][fr] + wsum[qh + 6][fr]);
  float rinv = 1.f / tot;
  if (w < 2 && l < 16) rsum[qh * 16 + fr] = rinv;

  // ---- Phase 2: att = e * rinv straight from registers (f32, NT) ----
  float* ao =
      att + (long)((b * 16 + h) * 2048 + q0 + qrow) * 2048 + ts * 512 + fg * 4;
#pragma unroll
  for (int i = 0; i < 32; ++i) {
    f16x4 e4 = s16[i];
    f32x4 o;
    o[0] = (float)e4[0] * rinv;
    o[1] = (float)e4[1] * rinv;
    o[2] = (float)e4[2] * rinv;
    o[3] = (float)e4[3] * rinv;
    __builtin_nontemporal_store(o, (f32x4*)(ao + i * 16));
  }

  // ---- Phase 3: partial PV over this wave's 512-t slice, 128-t chunks ----
  f16* eb = ebuf[w];
  const f16* vb =
      Vt + ((long)((b * 16 + h) * 64 + fr)) * 2048 + ts * 512 + fg * 8;
  f32x4 pacc[4] = {};
#pragma unroll
  for (int c = 0; c < 4; ++c) {
#pragma unroll
    for (int i2 = 0; i2 < 8; ++i2)
      *(f16x4*)(eb + fr * 136 + i2 * 16 + fg * 4) = s16[c * 8 + i2];
#pragma unroll
    for (int kt = 0; kt < 4; ++kt) {
      f16x8 af = *(const f16x8*)(eb + fr * 136 + kt * 32 + fg * 8);
#pragma unroll
      for (int vt = 0; vt < 4; ++vt) {
        f16x8 bf =
            *(const f16x8*)(vb + (long)vt * 16 * 2048 + c * 128 + kt * 32);
        pacc[vt] = mfma16(af, bf, pacc[vt]);
      }
    }
  }

  // ---- Phase 4: cross-wave reduce (partials reuse ebuf), write Pre ----
  float* pp = (float*)eb;
#pragma unroll
  for (int vt = 0; vt < 4; ++vt)
#pragma unroll
    for (int r = 0; r < 4; ++r)
      pp[(fg * 4 + r) * 64 + vt * 16 + fr] = pacc[vt][r];
  __syncthreads();
  {
    const int q = tid >> 4, v4 = (tid & 15) * 4;
    f32x4 p4 = {0.f, 0.f, 0.f, 0.f};
#pragma unroll
    for (int t4 = 0; t4 < 4; ++t4) {
      f32x4 u4 = *(const f32x4*)((const float*)ebuf[(q >> 4) + 2 * t4] +
                                 (q & 15) * 64 + v4);
      p4 += u4;
    }
    float ri = rsum[q];
    f16x4 o;
    o[0] = (f16)(p4[0] * ri);
    o[1] = (f16)(p4[1] * ri);
    o[2] = (f16)(p4[2] * ri);
    o[3] = (f16)(p4[3] * ri);
    *(f16x4*)(Pre + (long)(b * 2048 + q0 + q) * 1024 + h * 64 + v4) = o;
  }
}

extern "C" void kernel_launch(void* const* d_in, const int* in_sizes, int n_in,
                              void* d_out, int out_size, void* d_ws,
                              size_t ws_size, hipStream_t stream) {
  const float* qinput = (const float*)d_in[0];   // (2,2048,1024)
  const float* kvinput = (const float*)d_in[1];  // (2,2048,1024)
  const int* qtmask = (const int*)d_in[2];       // (2,2048,2048)
  const float* wq = (const float*)d_in[3];       // (16,1024,64)
  const float* wk = (const float*)d_in[4];
  const float* wv = (const float*)d_in[5];
  const float* wo = (const float*)d_in[6];       // (16,64,1024)
  float* out = (float*)d_out;                    // (2,2048,1024) f32
  float* att = out + (long)2 * 2048 * 1024;      // (2,16,2048,2048) f32

  char* ws = (char*)d_ws;
  f16* Xq = (f16*)(ws);                       // 8 MiB
  f16* Xkv = (f16*)(ws + 8388608);            // 8 MiB
  f16* WqT = (f16*)(ws + 16777216);           // 2 MiB
  f16* WkT = (f16*)(ws + 18874368);           // 2 MiB (contig with WvT)
  f16* WvT = (f16*)(ws + 20971520);           // 2 MiB
  f16* WoT = (f16*)(ws + 23068672);           // 2 MiB
  f16* Qm = (f16*)(ws + 25165824);            // 8 MiB
  f16* KVm = (f16*)(ws + 33554432);           // 16 MiB (K cols | V unused)
  f16* Vt = (f16*)(ws + 50331648);            // 8 MiB
  f16* Pre = (f16*)(ws + 58720256);           // 8 MiB
  unsigned* Mb = (unsigned*)(ws + 67108864);  // 1 MiB

  k_prep<<<dim3(10240), dim3(256), 0, stream>>>(qinput, kvinput, qtmask, wq,
                                                wk, wv, wo, Xq, Xkv, Mb, WqT,
                                                WkT, WvT, WoT);
  k_gemm_qkv<<<dim3(24, 32), dim3(256), 0, stream>>>(Xq, WqT, Qm, Xkv, WkT,
                                                     KVm, Vt);
  k_attn<<<dim3(64, 16, 2), dim3(512), 0, stream>>>(Qm, KVm, Vt, Mb, att, Pre,
                                                    2048);
  k_gemm_out<<<dim3(8, 32), dim3(256), 0, stream>>>(Pre, WoT, out);
}

// Round 8
// 351.202 us; speedup vs baseline: 1.0719x; 1.0719x over previous
//
#include <hip/hip_runtime.h>

typedef _Float16 f16;
typedef __attribute__((ext_vector_type(4))) _Float16 f16x4;
typedef __attribute__((ext_vector_type(8))) _Float16 f16x8;
typedef __attribute__((ext_vector_type(4))) float f32x4;

#define GLDS16(gp, lp)                                                        \
  __builtin_amdgcn_global_load_lds(                                           \
      (const __attribute__((address_space(1))) void*)(gp),                    \
      (__attribute__((address_space(3))) void*)(lp), 16, 0, 0)

__device__ __forceinline__ f32x4 mfma16(f16x8 a, f16x8 b, f32x4 c) {
  return __builtin_amdgcn_mfma_f32_16x16x32_f16(a, b, c, 0, 0, 0);
}

// ---------------- fused prep: cvt x2 | mask | weight transposes ----------------
// grid.x: [0,4096) cvt qin (kscale*log2e folded); [4096,8192) cvt kvin;
//         [8192,9216) mask; [9216,10240) tr32 of wq/wk/wv/wo
__global__ __launch_bounds__(256) void k_prep(
    const float* __restrict__ qin, const float* __restrict__ kvin,
    const int* __restrict__ qt, const float* __restrict__ wq,
    const float* __restrict__ wk, const float* __restrict__ wv,
    const float* __restrict__ wo, f16* __restrict__ Xq, f16* __restrict__ Xkv,
    unsigned* __restrict__ Mb, f16* __restrict__ WqT, f16* __restrict__ WkT,
    f16* __restrict__ WvT, f16* __restrict__ WoT) {
  __shared__ float tile[64][65];
  const int bx = blockIdx.x, tid = threadIdx.x;
  if (bx < 8192) {
    const float* s = bx < 4096 ? qin : kvin;
    f16* d = bx < 4096 ? Xq : Xkv;
    const float sc = bx < 4096 ? 0.18033688f : 1.0f;  // 0.125*log2(e) into Q
    int i = ((bx & 4095) * 256 + tid) * 4;
    float4 v = *(const float4*)(s + i);
    f16x4 h;
    h[0] = (f16)(v.x * sc); h[1] = (f16)(v.y * sc);
    h[2] = (f16)(v.z * sc); h[3] = (f16)(v.w * sc);
    *(f16x4*)(d + i) = h;
    return;
  }
  if (bx < 9216) {
    int w = (bx - 8192) * 256 + tid;
    const int* p = qt + (long)w * 32;
    unsigned m = 0;
#pragma unroll
    for (int j4 = 0; j4 < 8; ++j4) {
      int4 v = *(const int4*)(p + j4 * 4);
      m |= (v.x == 0 ? 1u : 0u) << (j4 * 4 + 0);
      m |= (v.y == 0 ? 1u : 0u) << (j4 * 4 + 1);
      m |= (v.z == 0 ? 1u : 0u) << (j4 * 4 + 2);
      m |= (v.w == 0 ? 1u : 0u) << (j4 * 4 + 3);
    }
    Mb[w] = m;
    return;
  }
  // weight transposes: dst[c][r] = src[r][c], f32 -> f16
  int sgt = bx - 9216, which = sgt >> 8, t = sgt & 255;
  const float* src;
  f16* dst;
  int sldr, r0, c0;
  const int dldr = 1024;
  if (which == 0) {
    src = wq + (long)(t >> 4) * 65536; dst = WqT + (long)(t >> 4) * 65536;
    sldr = 64; r0 = (t & 15) * 64; c0 = 0;
  } else if (which == 1) {
    src = wk + (long)(t >> 4) * 65536; dst = WkT + (long)(t >> 4) * 65536;
    sldr = 64; r0 = (t & 15) * 64; c0 = 0;
  } else if (which == 2) {
    src = wv + (long)(t >> 4) * 65536; dst = WvT + (long)(t >> 4) * 65536;
    sldr = 64; r0 = (t & 15) * 64; c0 = 0;
  } else {
    src = wo; dst = WoT;
    sldr = 1024; r0 = (t >> 4) * 64; c0 = (t & 15) * 64;
  }
  int r = tid >> 2, cq = (tid & 3) * 16;
#pragma unroll
  for (int j = 0; j < 16; j += 4) {
    float4 v = *(const float4*)(src + (long)(r0 + r) * sldr + c0 + cq + j);
    tile[r][cq + j] = v.x; tile[r][cq + j + 1] = v.y;
    tile[r][cq + j + 2] = v.z; tile[r][cq + j + 3] = v.w;
  }
  __syncthreads();
  int c = tid >> 2, rq = (tid & 3) * 16;
  f16x8 h0, h1;
#pragma unroll
  for (int j = 0; j < 8; ++j) h0[j] = (f16)tile[rq + j][c];
#pragma unroll
  for (int j = 0; j < 8; ++j) h1[j] = (f16)tile[rq + 8 + j][c];
  f16* dp = dst + (long)(c0 + c) * dldr + r0 + rq;
  *(f16x8*)dp = h0;
  *(f16x8*)(dp + 8) = h1;
}

// ---------------- GEMM body: C[LxN] = A[LxK] * Bt[NxK]^T ----------------
// mode 0: f16 C row-major; mode 1: f32 C row-major;
// mode 2: V-transposed write — Cout is Vt (b,h,64,T), cols are [1024,2048)
__device__ __forceinline__ void gemm_body(const f16* __restrict__ A,
                                          const f16* __restrict__ Bt,
                                          void* __restrict__ Cout, int Kd,
                                          int N, int bxx, int byy, int mode,
                                          f16* Al, f16* Bl) {
  const int tid = threadIdx.x, l = tid & 63, w = tid >> 6;
  const int wm = w >> 1, wn = w & 1;
  const int m0 = byy * 128, n0 = bxx * 128;
  const int lr = l >> 2;
  const int lc = (l & 3) * 8;
  const int fr = l & 15;
  const int fk = (l >> 4) * 8;
  f32x4 acc[4][4] = {};
  for (int k0 = 0; k0 < Kd; k0 += 32) {
#pragma unroll
    for (int rd = 0; rd < 2; ++rd) {
      GLDS16(A + (long)(m0 + rd * 64 + w * 16 + lr) * Kd + k0 + lc,
             (char*)Al + rd * 4096 + w * 1024);
      GLDS16(Bt + (long)(n0 + rd * 64 + w * 16 + lr) * Kd + k0 + lc,
             (char*)Bl + rd * 4096 + w * 1024);
    }
    __syncthreads();
    f16x8 af[4], bf[4];
#pragma unroll
    for (int i = 0; i < 4; ++i) {
      af[i] = *(const f16x8*)(Al + (wm * 64 + i * 16 + fr) * 32 + fk);
      bf[i] = *(const f16x8*)(Bl + (wn * 64 + i * 16 + fr) * 32 + fk);
    }
#pragma unroll
    for (int i = 0; i < 4; ++i)
#pragma unroll
      for (int j = 0; j < 4; ++j)
        acc[i][j] = mfma16(af[i], bf[j], acc[i][j]);
    __syncthreads();
  }
  const int rb = (l >> 4) * 4;
#pragma unroll
  for (int i = 0; i < 4; ++i)
#pragma unroll
    for (int j = 0; j < 4; ++j) {
      int row = m0 + wm * 64 + i * 16 + rb;
      int col = n0 + wn * 64 + j * 16 + fr;
      if (mode == 2) {
        // Vt[b][col-1024][t] ; 4 consecutive t's = contiguous f16x4
        int col2 = col - 1024;
        long off = (long)(row >> 11) * 2097152 + (long)col2 * 2048 +
                   (row & 2047);
        f16x4 o;
        o[0] = (f16)acc[i][j][0]; o[1] = (f16)acc[i][j][1];
        o[2] = (f16)acc[i][j][2]; o[3] = (f16)acc[i][j][3];
        *(f16x4*)((f16*)Cout + off) = o;
      } else {
#pragma unroll
        for (int r = 0; r < 4; ++r) {
          if (mode == 1)
            ((float*)Cout)[(long)(row + r) * N + col] = acc[i][j][r];
          else
            ((f16*)Cout)[(long)(row + r) * N + col] = (f16)acc[i][j][r];
        }
      }
    }
}

// Q-proj (x<8), K-proj (x in [8,16)), V-proj transposed (x in [16,24))
__global__ __launch_bounds__(256) void k_gemm_qkv(
    const f16* __restrict__ Xq, const f16* __restrict__ WqT,
    f16* __restrict__ Qm, const f16* __restrict__ Xkv,
    const f16* __restrict__ WkT, f16* __restrict__ KVm,
    f16* __restrict__ Vt) {
  __shared__ __attribute__((aligned(16))) f16 Al[128 * 32];
  __shared__ __attribute__((aligned(16))) f16 Bl[128 * 32];
  if (blockIdx.x < 8) {
    gemm_body(Xq, WqT, (void*)Qm, 1024, 1024, blockIdx.x, blockIdx.y, 0, Al,
              Bl);
  } else {
    int bxx = blockIdx.x - 8;
    if (bxx < 8)
      gemm_body(Xkv, WkT, (void*)KVm, 1024, 2048, bxx, blockIdx.y, 0, Al, Bl);
    else
      gemm_body(Xkv, WkT, (void*)Vt, 1024, 2048, bxx, blockIdx.y, 2, Al, Bl);
  }
}

__global__ __launch_bounds__(256) void k_gemm_out(const f16* __restrict__ Pre,
                                                  const f16* __restrict__ WoT,
                                                  float* __restrict__ out) {
  __shared__ __attribute__((aligned(16))) f16 Al[128 * 32];
  __shared__ __attribute__((aligned(16))) f16 Bl[128 * 32];
  gemm_body(Pre, WoT, (void*)out, 1024, 1024, blockIdx.x, blockIdx.y, 1, Al,
            Bl);
}

// ---------------- fused attention (QBLK=16, 256 threads, 4 waves) ----------
// Swapped QK^T; no max pass; exp2 (scale pre-folded into Q); e in registers;
// att straight from registers (NT); per-wave PV partials via private LDS.
__global__ __launch_bounds__(256) void k_attn(
    const f16* __restrict__ Qm, const f16* __restrict__ Km,
    const f16* __restrict__ Vt, const unsigned* __restrict__ mb,
    float* __restrict__ att, f16* __restrict__ Pre, int ldk) {
  __shared__ unsigned mloc[16 * 68];
  __shared__ float wsum[4][16];
  __shared__ float rsum[16];
  __shared__ __attribute__((aligned(16))) f16 ebuf[4][16 * 136];
  const int qt = blockIdx.x, h = blockIdx.y, b = blockIdx.z;
  const int q0 = qt * 16;
  const int tid = threadIdx.x, l = tid & 63, w = tid >> 6;
  const int fr = l & 15, fg = l >> 4;

  // stage active-bitmask (16 rows x 64 words, stride 68)
  for (int i = tid; i < 1024; i += 256)
    mloc[(i >> 6) * 68 + (i & 63)] =
        mb[(long)(b * 2048 + q0 + (i >> 6)) * 64 + (i & 63)];

  // Q fragment (B-operand); kscale*log2(e) already folded upstream
  const f16* qb = Qm + (long)(b * 2048 + q0 + fr) * 1024 + h * 64 + fg * 8;
  f16x8 qf0 = *(const f16x8*)qb;
  f16x8 qf1 = *(const f16x8*)(qb + 32);
  __syncthreads();

  // ---- Phase 1: S^T = K Q^T -> exp2 inline -> e (f16) in regs + row sums ----
  const f16* kb = Km + (long)(b * 2048 + w * 512 + fr) * ldk + h * 64 + fg * 8;
  f16x8 ka0[2], ka1[2];
#pragma unroll
  for (int p = 0; p < 2; ++p) {
    ka0[p] = *(const f16x8*)(kb + (long)p * 16 * ldk);
    ka1[p] = *(const f16x8*)(kb + (long)p * 16 * ldk + 32);
  }
  f16x4 s16[32];
  float sm[4] = {0.f, 0.f, 0.f, 0.f};
#pragma unroll
  for (int i = 0; i < 32; ++i) {
    f16x8 k0 = ka0[i & 1], k1 = ka1[i & 1];
    if (i < 30) {
      ka0[i & 1] = *(const f16x8*)(kb + (long)(i + 2) * 16 * ldk);
      ka1[i & 1] = *(const f16x8*)(kb + (long)(i + 2) * 16 * ldk + 32);
    }
    f32x4 s = {};
    s = mfma16(k0, qf0, s);
    s = mfma16(k1, qf1, s);
    unsigned bits =
        (mloc[fr * 68 + w * 16 + (i >> 1)] >> ((i & 1) * 16 + fg * 4)) & 0xFu;
    f16x4 e4;
#pragma unroll
    for (int r = 0; r < 4; ++r) {
      float ev = ((bits >> r) & 1) ? __builtin_amdgcn_exp2f(s[r]) : 0.f;
      sm[r] += ev;
      e4[r] = (f16)ev;
    }
    s16[i] = e4;
  }
  float sa = (sm[0] + sm[1]) + (sm[2] + sm[3]);
  sa += __shfl_xor(sa, 16, 64);
  sa += __shfl_xor(sa, 32, 64);
  if (l < 16) wsum[w][fr] = sa;
  __syncthreads();
  float tot = (wsum[0][fr] + wsum[1][fr]) + (wsum[2][fr] + wsum[3][fr]);
  float rinv = 1.f / tot;
  if (w == 0 && l < 16) rsum[fr] = rinv;

  // ---- Phase 2: att = e * rinv straight from registers (f32, NT) ----
  float* ao =
      att + (long)((b * 16 + h) * 2048 + q0 + fr) * 2048 + w * 512 + fg * 4;
#pragma unroll
  for (int i = 0; i < 32; ++i) {
    f16x4 e4 = s16[i];
    f32x4 o;
    o[0] = (float)e4[0] * rinv;
    o[1] = (float)e4[1] * rinv;
    o[2] = (float)e4[2] * rinv;
    o[3] = (float)e4[3] * rinv;
    __builtin_nontemporal_store(o, (f32x4*)(ao + i * 16));
  }

  // ---- Phase 3: partial PV over this wave's 512-t slice, 128-t chunks ----
  f16* eb = ebuf[w];
  const f16* vb =
      Vt + ((long)((b * 16 + h) * 64 + fr)) * 2048 + w * 512 + fg * 8;
  f32x4 pacc[4] = {};
#pragma unroll
  for (int c = 0; c < 4; ++c) {
#pragma unroll
    for (int i2 = 0; i2 < 8; ++i2)
      *(f16x4*)(eb + fr * 136 + i2 * 16 + fg * 4) = s16[c * 8 + i2];
#pragma unroll
    for (int kt = 0; kt < 4; ++kt) {
      f16x8 af = *(const f16x8*)(eb + fr * 136 + kt * 32 + fg * 8);
#pragma unroll
      for (int vt = 0; vt < 4; ++vt) {
        f16x8 bf =
            *(const f16x8*)(vb + (long)vt * 16 * 2048 + c * 128 + kt * 32);
        pacc[vt] = mfma16(af, bf, pacc[vt]);
      }
    }
  }

  // ---- Phase 4: cross-wave reduce (partials reuse ebuf), write Pre ----
  float* pp = (float*)eb;
#pragma unroll
  for (int vt = 0; vt < 4; ++vt)
#pragma unroll
    for (int r = 0; r < 4; ++r)
      pp[(fg * 4 + r) * 64 + vt * 16 + fr] = pacc[vt][r];
  __syncthreads();
  {
    const int q = tid >> 4, v4 = (tid & 15) * 4;
    f32x4 p4 = {0.f, 0.f, 0.f, 0.f};
#pragma unroll
    for (int w4 = 0; w4 < 4; ++w4) {
      f32x4 t4 = *(const f32x4*)((const float*)ebuf[w4] + q * 64 + v4);
      p4 += t4;
    }
    float ri = rsum[q];
    f16x4 o;
    o[0] = (f16)(p4[0] * ri);
    o[1] = (f16)(p4[1] * ri);
    o[2] = (f16)(p4[2] * ri);
    o[3] = (f16)(p4[3] * ri);
    *(f16x4*)(Pre + (long)(b * 2048 + q0 + q) * 1024 + h * 64 + v4) = o;
  }
}

extern "C" void kernel_launch(void* const* d_in, const int* in_sizes, int n_in,
                              void* d_out, int out_size, void* d_ws,
                              size_t ws_size, hipStream_t stream) {
  const float* qinput = (const float*)d_in[0];   // (2,2048,1024)
  const float* kvinput = (const float*)d_in[1];  // (2,2048,1024)
  const int* qtmask = (const int*)d_in[2];       // (2,2048,2048)
  const float* wq = (const float*)d_in[3];       // (16,1024,64)
  const float* wk = (const float*)d_in[4];
  const float* wv = (const float*)d_in[5];
  const float* wo = (const float*)d_in[6];       // (16,64,1024)
  float* out = (float*)d_out;                    // (2,2048,1024) f32
  float* att = out + (long)2 * 2048 * 1024;      // (2,16,2048,2048) f32

  char* ws = (char*)d_ws;
  f16* Xq = (f16*)(ws);                       // 8 MiB
  f16* Xkv = (f16*)(ws + 8388608);            // 8 MiB
  f16* WqT = (f16*)(ws + 16777216);           // 2 MiB
  f16* WkT = (f16*)(ws + 18874368);           // 2 MiB (contig with WvT)
  f16* WvT = (f16*)(ws + 20971520);           // 2 MiB
  f16* WoT = (f16*)(ws + 23068672);           // 2 MiB
  f16* Qm = (f16*)(ws + 25165824);            // 8 MiB
  f16* KVm = (f16*)(ws + 33554432);           // 16 MiB (K cols | V unused)
  f16* Vt = (f16*)(ws + 50331648);            // 8 MiB
  f16* Pre = (f16*)(ws + 58720256);           // 8 MiB
  unsigned* Mb = (unsigned*)(ws + 67108864);  // 1 MiB

  k_prep<<<dim3(10240), dim3(256), 0, stream>>>(qinput, kvinput, qtmask, wq,
                                                wk, wv, wo, Xq, Xkv, Mb, WqT,
                                                WkT, WvT, WoT);
  k_gemm_qkv<<<dim3(24, 32), dim3(256), 0, stream>>>(Xq, WqT, Qm, Xkv, WkT,
                                                     KVm, Vt);
  k_attn<<<dim3(128, 16, 2), dim3(256), 0, stream>>>(Qm, KVm, Vt, Mb, att, Pre,
                                                     2048);
  k_gemm_out<<<dim3(8, 32), dim3(256), 0, stream>>>(Pre, WoT, out);
}